// Round 17
// baseline (123.788 us; speedup 1.0000x reference)
//
#include <hip/hip_runtime.h>
#include <stdint.h>

#define D_DIM 512
#define NSTEPS 10
#define ALPHA0 0.1f
#define DT_C 0.1f
#define BETA_C 2.8982753492378875f

typedef __attribute__((ext_vector_type(8))) short short8;
typedef __attribute__((ext_vector_type(4))) float floatx4;
typedef __attribute__((ext_vector_type(4))) unsigned short ushortx4;

__device__ __forceinline__ unsigned short f32_to_bf16(float f) {
    union { float f; uint32_t u; } v;
    v.f = f;
    uint32_t u = v.u;
    return (unsigned short)((u + 0x7FFFu + ((u >> 16) & 1u)) >> 16);
}

// ---------------------------------------------------------------------------
// Kernel 1: build L_rw and store PRE-TILED in MFMA fragment order (round 13).
// Tile (eg32, kk) stored as two 1KB halves; byte l*16 of a half is exactly
// the fragment MFMA-lane l consumes.
// ---------------------------------------------------------------------------
__global__ __launch_bounds__(64) void prep_kernel(
    const float* __restrict__ W,
    unsigned short* __restrict__ Ltl)    // 512 KiB, tiled layout
{
    const int e = blockIdx.x;
    const int lane = threadIdx.x;
    const float* w = W + (size_t)e * D_DIM + lane * 8;
    const float4 v0 = *(const float4*)w;
    const float4 v1 = *(const float4*)(w + 4);
    float a[8] = { fabsf(v0.x), fabsf(v0.y), fabsf(v0.z), fabsf(v0.w),
                   fabsf(v1.x), fabsf(v1.y), fabsf(v1.z), fabsf(v1.w) };
    float s = a[0] + a[1] + a[2] + a[3] + a[4] + a[5] + a[6] + a[7];
#pragma unroll
    for (int off = 1; off < 64; off <<= 1) s += __shfl_xor(s, off, 64);
    const float inv = 1.0f / fmaxf(s, 1e-8f);
    short8 pk;
#pragma unroll
    for (int j = 0; j < 8; ++j) {
        const float diag = ((lane * 8 + j) == e) ? 1.0f : 0.0f;
        pk[j] = (short)f32_to_bf16(diag - a[j] * inv);
    }
    const int eg = e >> 5, half = (e >> 4) & 1, r = e & 15;
    const int kk = lane >> 2, qp = lane & 3;
    char* dst = (char*)Ltl + ((size_t)(eg * 32 + kk * 2 + half) << 10)
                + ((size_t)(qp * 16 + r) << 4);
    *(short8*)dst = pk;
}

// ---------------------------------------------------------------------------
// Kernel 2: full 10-step settle, ONE launch, 32 blocks x 512 thr (8 waves).
// ROUND-17: eliminate the L LDS round-trip (round-14/16 chain was LDS-pipe
// bound: 1.3 MB/step/CU ~= the 7.7us/step wall). Tiled Ltl makes every L
// fragment a contiguous coalesced 1KB burst -> load L2->VGPR directly.
//   wave w owns e-rows [64w, 64w+64) = 4 m-frags; per kk: 4 x 1KB frag loads
//   + 1 Abuf b-read + 4 MFMAs. 8 waves = 2/SIMD for TLP.
// Register budget: empirical allocator cap ~= 65536/block_threads
//   (256thr->256 meas r15, 1024thr->64 meas r5-10) => 512thr -> 128.
//   Census: At/Bt 32 + acc 16 + a-staging ~64 (2-deep) + addr ~10 = ~122 < 128.
// LDS: Abuf only (16 KB). Plain __syncthreads per step (no DMA to preserve).
// Epilogue: Gtl = g*A10 + (1-g)I PRE-TILED (fragment order), eg16 = wave*4+m.
// ---------------------------------------------------------------------------
__global__ __launch_bounds__(512) void chain_kernel(
    const unsigned short* __restrict__ Ltl,   // tiled L (see prep)
    const float* __restrict__ prec,
    const float* __restrict__ gate_alpha,
    unsigned short* __restrict__ Gtl)         // tiled G, diag folded
{
    const int tid = threadIdx.x;
    const int wave = tid >> 6, lane = tid & 63;
    const int lrow = lane & 15, q = lane >> 4;
    const int c_glob = blockIdx.x * 16 + lrow;
    const int ebase = wave * 64;               // 4 m-frags

    __shared__ unsigned short Abuf[16 * D_DIM];    // 16 KiB, swizzled [c][d]
    char* abuf = (char*)Abuf;

    floatx4 At[4], Bt[4];
#pragma unroll
    for (int m = 0; m < 4; ++m) {
#pragma unroll
        for (int j = 0; j < 4; ++j) {
            const int e = ebase + m * 16 + q * 4 + j;
            At[m][j] = (e == c_glob) ? 1.0f : 0.0f;
            Bt[m][j] = 0.0f;
        }
    }

    // init Abuf with A0 = I (waves 0..7 cover d-cols 0..511 via ebase)
#pragma unroll
    for (int m = 0; m < 4; ++m) {
        ushortx4 pk;
#pragma unroll
        for (int j = 0; j < 4; ++j) pk[j] = f32_to_bf16(At[m][j]);
        int byte = lrow * 1024 + (ebase + m * 16 + q * 4) * 2;
        byte ^= (lrow & 7) << 4;
        *(ushortx4*)(abuf + byte) = pk;
    }
    __syncthreads();

    // lane's L-frag base: frag (m,kk) at
    //   lb + (m>>1)*32768 + (kk*2 + (m&1))*1024      (eg32 = 2*wave + (m>>1))
    const char* lb = (const char*)Ltl + ((size_t)(wave * 2) << 15) + (size_t)lane * 16;

    for (int step = 0; step < NSTEPS; ++step) {
        floatx4 acc[4] = {};
#pragma unroll
        for (int kk = 0; kk < 16; ++kk) {
            short8 a[4];
#pragma unroll
            for (int m = 0; m < 4; ++m)
                a[m] = *(const short8*)(lb + ((m >> 1) << 15) + ((kk * 2 + (m & 1)) << 10));
            int bbyte = lrow * 1024 + kk * 64 + q * 16;
            bbyte ^= (lrow & 7) << 4;
            const short8 b = *(const short8*)(abuf + bbyte);
#pragma unroll
            for (int m = 0; m < 4; ++m)
                acc[m] = __builtin_amdgcn_mfma_f32_16x16x32_bf16(a[m], b, acc[m], 0, 0, 0);
        }

        // state update; prec reloaded per step (L1-hit, saves 16 regs)
#pragma unroll
        for (int m = 0; m < 4; ++m) {
            const float4 pm = *(const float4*)(prec + ebase + m * 16 + q * 4);
            const float pa[4] = { pm.x, pm.y, pm.z, pm.w };
#pragma unroll
            for (int j = 0; j < 4; ++j) {
                const int e = ebase + m * 16 + q * 4 + j;
                const float p = pa[j];
                const float tgt = (e == c_glob) ? p : 0.0f;
                const float force = -acc[m][j] - (ALPHA0 + p) * At[m][j]
                                    + tgt - BETA_C * Bt[m][j];
                Bt[m][j] += DT_C * force;
                At[m][j] += DT_C * Bt[m][j];
            }
        }

        if (step < NSTEPS - 1) {
            __syncthreads();
#pragma unroll
            for (int m = 0; m < 4; ++m) {
                ushortx4 pk;
#pragma unroll
                for (int j = 0; j < 4; ++j) pk[j] = f32_to_bf16(At[m][j]);
                int byte = lrow * 1024 + (ebase + m * 16 + q * 4) * 2;
                byte ^= (lrow & 7) << 4;
                *(ushortx4*)(abuf + byte) = pk;
            }
            __syncthreads();
        }
    }

    // epilogue: G = g*A10 + (1-g)I, written PRE-TILED (fragment order).
    // E = ebase+m*16+q*4+j -> eg16 = wave*4+m; D = c_glob, kt = c_glob>>5.
    const float g = tanhf(gate_alpha[0]);
    const int kt = c_glob >> 5;
    const int lq = ((c_glob >> 3) & 3) * 16;
    const int jb = (c_glob & 7) * 2;
#pragma unroll
    for (int m = 0; m < 4; ++m) {
        char* tbase = (char*)Gtl + ((size_t)((wave * 4 + m) * 16 + kt) << 10);
#pragma unroll
        for (int j = 0; j < 4; ++j) {
            const int e = ebase + m * 16 + q * 4 + j;
            float val = g * At[m][j];
            if (e == c_glob) val += (1.0f - g);
            *(unsigned short*)(tbase + (q * 4 + j + lq) * 16 + jb) = f32_to_bf16(val);
        }
    }
}

// ---------------------------------------------------------------------------
// Kernel 3: out = Hbf @ G^T (diag folded into G).
// EXACT round-15/16 structure (measured ~22us): 64-row tiles, 256 blocks x
// 256 thr (4 waves); H in 64 KB swizzled LDS; G direct from L2 in fragment
// order (Gtl, 1KB coalesced per frag). acc[4][8] + a[4] + b[4] ~= 210 regs.
// ---------------------------------------------------------------------------
__global__ __launch_bounds__(256) void out_gemm(
    const float* __restrict__ H,              // [16384][512]
    const unsigned short* __restrict__ Gtl,   // tiled G, diag folded
    float* __restrict__ Out)
{
    const int r0 = blockIdx.x * 64;
    const int tid = threadIdx.x;
    const int wave = tid >> 6, lane = tid & 63;
    const int lrow = lane & 15, q = lane >> 4;

    __shared__ unsigned short hlds[64 * D_DIM];  // 64 KiB, swizzled
    char* lds = (char*)hlds;

    // stage H: wave w rows [16w, 16w+16); lane covers cols [8*lane, +8)
#pragma unroll
    for (int i = 0; i < 16; ++i) {
        const int row = wave * 16 + i;
        const float* src = H + (size_t)(r0 + row) * D_DIM + lane * 8;
        const float4 v0 = *(const float4*)src;
        const float4 v1 = *(const float4*)(src + 4);
        short8 pk;
        pk[0] = (short)f32_to_bf16(v0.x); pk[1] = (short)f32_to_bf16(v0.y);
        pk[2] = (short)f32_to_bf16(v0.z); pk[3] = (short)f32_to_bf16(v0.w);
        pk[4] = (short)f32_to_bf16(v1.x); pk[5] = (short)f32_to_bf16(v1.y);
        pk[6] = (short)f32_to_bf16(v1.z); pk[7] = (short)f32_to_bf16(v1.w);
        int byte = row * 1024 + lane * 16;
        byte ^= (row & 7) << 4;
        *(short8*)(lds + byte) = pk;
    }
    __syncthreads();

    // this wave's G tiles: e-groups [wave*8, wave*8+8), all 16 k-tiles
    const char* gtb = (const char*)Gtl + ((size_t)(wave * 8 * 16) << 10)
                      + ((size_t)lane << 4);

    floatx4 acc[4][8] = {};
#pragma unroll
    for (int kk = 0; kk < 16; ++kk) {
        short8 a[4];
#pragma unroll
        for (int m = 0; m < 4; ++m) {
            const int row = m * 16 + lrow;
            int byte = row * 1024 + kk * 64 + q * 16;
            byte ^= (row & 7) << 4;
            a[m] = *(const short8*)(lds + byte);
        }
#pragma unroll
        for (int nh = 0; nh < 2; ++nh) {
            short8 b[4];
#pragma unroll
            for (int n = 0; n < 4; ++n)
                b[n] = *(const short8*)(gtb + ((size_t)((nh * 4 + n) * 16 + kk) << 10));
#pragma unroll
            for (int n = 0; n < 4; ++n)
#pragma unroll
                for (int m = 0; m < 4; ++m)
                    acc[m][nh * 4 + n] = __builtin_amdgcn_mfma_f32_16x16x32_bf16(
                        a[m], b[n], acc[m][nh * 4 + n], 0, 0, 0);
        }
    }

    // epilogue: Out[r][e] = acc (diag already in G)
#pragma unroll
    for (int m = 0; m < 4; ++m) {
#pragma unroll
        for (int j = 0; j < 4; ++j) {
            const int r = r0 + m * 16 + q * 4 + j;
#pragma unroll
            for (int n = 0; n < 8; ++n) {
                const int e = wave * 128 + n * 16 + lrow;
                Out[(size_t)r * D_DIM + e] = acc[m][n][j];
            }
        }
    }
}

// ---------------------------------------------------------------------------
extern "C" void kernel_launch(void* const* d_in, const int* in_sizes, int n_in,
                              void* d_out, int out_size, void* d_ws, size_t ws_size,
                              hipStream_t stream)
{
    const float* H    = (const float*)d_in[0];   // (4,4096,512)
    const float* W    = (const float*)d_in[1];   // (512,512)
    const float* gate = (const float*)d_in[2];   // (1,)
    const float* prec = (const float*)d_in[3];   // (512,)
    float* out = (float*)d_out;
    char* ws = (char*)d_ws;

    unsigned short* Ltl = (unsigned short*)(ws);                 // 512 KiB (tiled)
    unsigned short* Gtl = (unsigned short*)(ws + (512u << 10));  // 512 KiB (tiled)

    prep_kernel<<<dim3(D_DIM), dim3(64), 0, stream>>>(W, Ltl);

    chain_kernel<<<dim3(D_DIM / 16), dim3(512), 0, stream>>>(
        Ltl, prec, gate, Gtl);

    out_gemm<<<dim3(16384 / 64), dim3(256), 0, stream>>>(H, Gtl, out);
}

// Round 18
// 106.653 us; speedup vs baseline: 1.1607x; 1.1607x over previous
//
#include <hip/hip_runtime.h>
#include <stdint.h>

#define D_DIM 512
#define NSTEPS 10
#define ALPHA0 0.1f
#define DT_C 0.1f
#define BETA_C 2.8982753492378875f

typedef __attribute__((ext_vector_type(8))) short short8;
typedef __attribute__((ext_vector_type(4))) float floatx4;
typedef __attribute__((ext_vector_type(4))) unsigned short ushortx4;

__device__ __forceinline__ unsigned short f32_to_bf16(float f) {
    union { float f; uint32_t u; } v;
    v.f = f;
    uint32_t u = v.u;
    return (unsigned short)((u + 0x7FFFu + ((u >> 16) & 1u)) >> 16);
}

// ---------------------------------------------------------------------------
// Kernel 1: build L_rw and store PRE-TILED in MFMA fragment order (round 13).
// Tile (eg32, kk) stored as two 1KB halves; byte l*16 of a half is exactly
// the fragment MFMA-lane l consumes.
// ---------------------------------------------------------------------------
__global__ __launch_bounds__(64) void prep_kernel(
    const float* __restrict__ W,
    unsigned short* __restrict__ Ltl)    // 512 KiB, tiled layout
{
    const int e = blockIdx.x;
    const int lane = threadIdx.x;
    const float* w = W + (size_t)e * D_DIM + lane * 8;
    const float4 v0 = *(const float4*)w;
    const float4 v1 = *(const float4*)(w + 4);
    float a[8] = { fabsf(v0.x), fabsf(v0.y), fabsf(v0.z), fabsf(v0.w),
                   fabsf(v1.x), fabsf(v1.y), fabsf(v1.z), fabsf(v1.w) };
    float s = a[0] + a[1] + a[2] + a[3] + a[4] + a[5] + a[6] + a[7];
#pragma unroll
    for (int off = 1; off < 64; off <<= 1) s += __shfl_xor(s, off, 64);
    const float inv = 1.0f / fmaxf(s, 1e-8f);
    short8 pk;
#pragma unroll
    for (int j = 0; j < 8; ++j) {
        const float diag = ((lane * 8 + j) == e) ? 1.0f : 0.0f;
        pk[j] = (short)f32_to_bf16(diag - a[j] * inv);
    }
    const int eg = e >> 5, half = (e >> 4) & 1, r = e & 15;
    const int kk = lane >> 2, qp = lane & 3;
    char* dst = (char*)Ltl + ((size_t)(eg * 32 + kk * 2 + half) << 10)
                + ((size_t)(qp * 16 + r) << 4);
    *(short8*)dst = pk;
}

// ---------------------------------------------------------------------------
// Kernel 2: full 10-step settle, ONE launch, 32 blocks x 512 thr (8 waves).
// Round-17 structure (correctness proven, absmax 0.03125) with the spill
// fix: rounds 15/17 spilled NOT from the census (~88 regs) but from the
// FULLY-UNROLLED kk loop letting the scheduler pipeline all 64 fragment
// loads (~360 live regs at any cap).
//   ROUND-18 changes:
//   - #pragma unroll 4 on the kk loop: 8 visible loads/iter; 3-deep
//     cross-iter pipelining tops out ~150 regs.
//   - __launch_bounds__(512, 1): request the full 256-reg budget.
//   - prec hoisted to registers (16) so no global load sits in the loop.
// L goes L2 -> VGPR directly (tiled Ltl: every frag = contiguous coalesced
// 1KB burst). LDS holds only Abuf (16 KB). Plain __syncthreads per step.
// Epilogue: Gtl = g*A10 + (1-g)I PRE-TILED (fragment order), eg16 = wave*4+m.
// ---------------------------------------------------------------------------
__global__ __launch_bounds__(512, 1) void chain_kernel(
    const unsigned short* __restrict__ Ltl,   // tiled L (see prep)
    const float* __restrict__ prec,
    const float* __restrict__ gate_alpha,
    unsigned short* __restrict__ Gtl)         // tiled G, diag folded
{
    const int tid = threadIdx.x;
    const int wave = tid >> 6, lane = tid & 63;
    const int lrow = lane & 15, q = lane >> 4;
    const int c_glob = blockIdx.x * 16 + lrow;
    const int ebase = wave * 64;               // 4 m-frags

    __shared__ unsigned short Abuf[16 * D_DIM];    // 16 KiB, swizzled [c][d]
    char* abuf = (char*)Abuf;

    // prec hoisted: 16 regs, no global loads inside the step loop
    float pr[4][4];
#pragma unroll
    for (int m = 0; m < 4; ++m) {
        const float4 pm = *(const float4*)(prec + ebase + m * 16 + q * 4);
        pr[m][0] = pm.x; pr[m][1] = pm.y; pr[m][2] = pm.z; pr[m][3] = pm.w;
    }

    floatx4 At[4], Bt[4];
#pragma unroll
    for (int m = 0; m < 4; ++m) {
#pragma unroll
        for (int j = 0; j < 4; ++j) {
            const int e = ebase + m * 16 + q * 4 + j;
            At[m][j] = (e == c_glob) ? 1.0f : 0.0f;
            Bt[m][j] = 0.0f;
        }
    }

    // init Abuf with A0 = I (8 waves x 4 m-frags cover d-cols 0..511)
#pragma unroll
    for (int m = 0; m < 4; ++m) {
        ushortx4 pk;
#pragma unroll
        for (int j = 0; j < 4; ++j) pk[j] = f32_to_bf16(At[m][j]);
        int byte = lrow * 1024 + (ebase + m * 16 + q * 4) * 2;
        byte ^= (lrow & 7) << 4;
        *(ushortx4*)(abuf + byte) = pk;
    }
    __syncthreads();

    // lane's L-frag base: frag (m,kk) at
    //   lb + (m>>1)*32768 + (kk*2 + (m&1))*1024      (eg32 = 2*wave + (m>>1))
    const char* lb = (const char*)Ltl + ((size_t)(wave * 2) << 15) + (size_t)lane * 16;

    for (int step = 0; step < NSTEPS; ++step) {
        floatx4 acc[4] = {};
#pragma unroll 4
        for (int kk = 0; kk < 16; ++kk) {
            short8 a[4];
#pragma unroll
            for (int m = 0; m < 4; ++m)
                a[m] = *(const short8*)(lb + ((m >> 1) << 15) + ((kk * 2 + (m & 1)) << 10));
            int bbyte = lrow * 1024 + kk * 64 + q * 16;
            bbyte ^= (lrow & 7) << 4;
            const short8 b = *(const short8*)(abuf + bbyte);
#pragma unroll
            for (int m = 0; m < 4; ++m)
                acc[m] = __builtin_amdgcn_mfma_f32_16x16x32_bf16(a[m], b, acc[m], 0, 0, 0);
        }

        // state update (f32, registers only)
#pragma unroll
        for (int m = 0; m < 4; ++m) {
#pragma unroll
            for (int j = 0; j < 4; ++j) {
                const int e = ebase + m * 16 + q * 4 + j;
                const float p = pr[m][j];
                const float tgt = (e == c_glob) ? p : 0.0f;
                const float force = -acc[m][j] - (ALPHA0 + p) * At[m][j]
                                    + tgt - BETA_C * Bt[m][j];
                Bt[m][j] += DT_C * force;
                At[m][j] += DT_C * Bt[m][j];
            }
        }

        if (step < NSTEPS - 1) {
            __syncthreads();
#pragma unroll
            for (int m = 0; m < 4; ++m) {
                ushortx4 pk;
#pragma unroll
                for (int j = 0; j < 4; ++j) pk[j] = f32_to_bf16(At[m][j]);
                int byte = lrow * 1024 + (ebase + m * 16 + q * 4) * 2;
                byte ^= (lrow & 7) << 4;
                *(ushortx4*)(abuf + byte) = pk;
            }
            __syncthreads();
        }
    }

    // epilogue: G = g*A10 + (1-g)I, written PRE-TILED (fragment order).
    // E = ebase+m*16+q*4+j -> eg16 = wave*4+m; D = c_glob, kt = c_glob>>5.
    const float g = tanhf(gate_alpha[0]);
    const int kt = c_glob >> 5;
    const int lq = ((c_glob >> 3) & 3) * 16;
    const int jb = (c_glob & 7) * 2;
#pragma unroll
    for (int m = 0; m < 4; ++m) {
        char* tbase = (char*)Gtl + ((size_t)((wave * 4 + m) * 16 + kt) << 10);
#pragma unroll
        for (int j = 0; j < 4; ++j) {
            const int e = ebase + m * 16 + q * 4 + j;
            float val = g * At[m][j];
            if (e == c_glob) val += (1.0f - g);
            *(unsigned short*)(tbase + (q * 4 + j + lq) * 16 + jb) = f32_to_bf16(val);
        }
    }
}

// ---------------------------------------------------------------------------
// Kernel 3: out = Hbf @ G^T (diag folded into G).
// EXACT round-15/16 structure (measured ~22us): 64-row tiles, 256 blocks x
// 256 thr (4 waves); H in 64 KB swizzled LDS; G direct from L2 in fragment
// order (Gtl, 1KB coalesced per frag). acc[4][8] + a[4] + b[4] ~= 210 regs.
// ---------------------------------------------------------------------------
__global__ __launch_bounds__(256) void out_gemm(
    const float* __restrict__ H,              // [16384][512]
    const unsigned short* __restrict__ Gtl,   // tiled G, diag folded
    float* __restrict__ Out)
{
    const int r0 = blockIdx.x * 64;
    const int tid = threadIdx.x;
    const int wave = tid >> 6, lane = tid & 63;
    const int lrow = lane & 15, q = lane >> 4;

    __shared__ unsigned short hlds[64 * D_DIM];  // 64 KiB, swizzled
    char* lds = (char*)hlds;

    // stage H: wave w rows [16w, 16w+16); lane covers cols [8*lane, +8)
#pragma unroll
    for (int i = 0; i < 16; ++i) {
        const int row = wave * 16 + i;
        const float* src = H + (size_t)(r0 + row) * D_DIM + lane * 8;
        const float4 v0 = *(const float4*)src;
        const float4 v1 = *(const float4*)(src + 4);
        short8 pk;
        pk[0] = (short)f32_to_bf16(v0.x); pk[1] = (short)f32_to_bf16(v0.y);
        pk[2] = (short)f32_to_bf16(v0.z); pk[3] = (short)f32_to_bf16(v0.w);
        pk[4] = (short)f32_to_bf16(v1.x); pk[5] = (short)f32_to_bf16(v1.y);
        pk[6] = (short)f32_to_bf16(v1.z); pk[7] = (short)f32_to_bf16(v1.w);
        int byte = row * 1024 + lane * 16;
        byte ^= (row & 7) << 4;
        *(short8*)(lds + byte) = pk;
    }
    __syncthreads();

    // this wave's G tiles: e-groups [wave*8, wave*8+8), all 16 k-tiles
    const char* gtb = (const char*)Gtl + ((size_t)(wave * 8 * 16) << 10)
                      + ((size_t)lane << 4);

    floatx4 acc[4][8] = {};
#pragma unroll
    for (int kk = 0; kk < 16; ++kk) {
        short8 a[4];
#pragma unroll
        for (int m = 0; m < 4; ++m) {
            const int row = m * 16 + lrow;
            int byte = row * 1024 + kk * 64 + q * 16;
            byte ^= (row & 7) << 4;
            a[m] = *(const short8*)(lds + byte);
        }
#pragma unroll
        for (int nh = 0; nh < 2; ++nh) {
            short8 b[4];
#pragma unroll
            for (int n = 0; n < 4; ++n)
                b[n] = *(const short8*)(gtb + ((size_t)((nh * 4 + n) * 16 + kk) << 10));
#pragma unroll
            for (int n = 0; n < 4; ++n)
#pragma unroll
                for (int m = 0; m < 4; ++m)
                    acc[m][nh * 4 + n] = __builtin_amdgcn_mfma_f32_16x16x32_bf16(
                        a[m], b[n], acc[m][nh * 4 + n], 0, 0, 0);
        }
    }

    // epilogue: Out[r][e] = acc (diag already in G)
#pragma unroll
    for (int m = 0; m < 4; ++m) {
#pragma unroll
        for (int j = 0; j < 4; ++j) {
            const int r = r0 + m * 16 + q * 4 + j;
#pragma unroll
            for (int n = 0; n < 8; ++n) {
                const int e = wave * 128 + n * 16 + lrow;
                Out[(size_t)r * D_DIM + e] = acc[m][n][j];
            }
        }
    }
}

// ---------------------------------------------------------------------------
extern "C" void kernel_launch(void* const* d_in, const int* in_sizes, int n_in,
                              void* d_out, int out_size, void* d_ws, size_t ws_size,
                              hipStream_t stream)
{
    const float* H    = (const float*)d_in[0];   // (4,4096,512)
    const float* W    = (const float*)d_in[1];   // (512,512)
    const float* gate = (const float*)d_in[2];   // (1,)
    const float* prec = (const float*)d_in[3];   // (512,)
    float* out = (float*)d_out;
    char* ws = (char*)d_ws;

    unsigned short* Ltl = (unsigned short*)(ws);                 // 512 KiB (tiled)
    unsigned short* Gtl = (unsigned short*)(ws + (512u << 10));  // 512 KiB (tiled)

    prep_kernel<<<dim3(D_DIM), dim3(64), 0, stream>>>(W, Ltl);

    chain_kernel<<<dim3(D_DIM / 16), dim3(512), 0, stream>>>(
        Ltl, prec, gate, Gtl);

    out_gemm<<<dim3(16384 / 64), dim3(256), 0, stream>>>(H, Gtl, out);
}

// Round 19
// 83.746 us; speedup vs baseline: 1.4781x; 1.2735x over previous
//
#include <hip/hip_runtime.h>
#include <stdint.h>

#define D_DIM 512
#define NSTEPS 10
#define ALPHA0 0.1f
#define DT_C 0.1f
#define BETA_C 2.8982753492378875f
#define H_ELEMS (16384u * 512u)

typedef __attribute__((ext_vector_type(8))) short short8;
typedef __attribute__((ext_vector_type(4))) float floatx4;
typedef __attribute__((ext_vector_type(4))) unsigned short ushortx4;

__device__ __forceinline__ unsigned short f32_to_bf16(float f) {
    union { float f; uint32_t u; } v;
    v.f = f;
    uint32_t u = v.u;
    return (unsigned short)((u + 0x7FFFu + ((u >> 16) & 1u)) >> 16);
}

__device__ __forceinline__ short8 pack8(const float4 v0, const float4 v1) {
    short8 pk;
    pk[0] = (short)f32_to_bf16(v0.x); pk[1] = (short)f32_to_bf16(v0.y);
    pk[2] = (short)f32_to_bf16(v0.z); pk[3] = (short)f32_to_bf16(v0.w);
    pk[4] = (short)f32_to_bf16(v1.x); pk[5] = (short)f32_to_bf16(v1.y);
    pk[6] = (short)f32_to_bf16(v1.z); pk[7] = (short)f32_to_bf16(v1.w);
    return pk;
}

// ---------------------------------------------------------------------------
// Kernel 1: build L_rw and store PRE-TILED in MFMA fragment order (round 13).
// ---------------------------------------------------------------------------
__global__ __launch_bounds__(64) void prep_kernel(
    const float* __restrict__ W,
    unsigned short* __restrict__ Ltl)    // 512 KiB, tiled layout
{
    const int e = blockIdx.x;
    const int lane = threadIdx.x;
    const float* w = W + (size_t)e * D_DIM + lane * 8;
    const float4 v0 = *(const float4*)w;
    const float4 v1 = *(const float4*)(w + 4);
    float a[8] = { fabsf(v0.x), fabsf(v0.y), fabsf(v0.z), fabsf(v0.w),
                   fabsf(v1.x), fabsf(v1.y), fabsf(v1.z), fabsf(v1.w) };
    float s = a[0] + a[1] + a[2] + a[3] + a[4] + a[5] + a[6] + a[7];
#pragma unroll
    for (int off = 1; off < 64; off <<= 1) s += __shfl_xor(s, off, 64);
    const float inv = 1.0f / fmaxf(s, 1e-8f);
    short8 pk;
#pragma unroll
    for (int j = 0; j < 8; ++j) {
        const float diag = ((lane * 8 + j) == e) ? 1.0f : 0.0f;
        pk[j] = (short)f32_to_bf16(diag - a[j] * inv);
    }
    const int eg = e >> 5, half = (e >> 4) & 1, r = e & 15;
    const int kk = lane >> 2, qp = lane & 3;
    char* dst = (char*)Ltl + ((size_t)(eg * 32 + kk * 2 + half) << 10)
                + ((size_t)(qp * 16 + r) << 4);
    *(short8*)dst = pk;
}

// ---------------------------------------------------------------------------
// Kernel 2: fused {10-step settle (blocks 0..31)} + {H->bf16 cvt (blocks 32+)}.
// Chain: 32 blocks x 1024 thr (16 waves); wave w owns e-rows [32w,32w+32)
// (2 m-frags) -> 4 waves/SIMD TLP (round 18 had only 2). L loaded L2->VGPR
// directly from tiled Ltl (frag = coalesced 1KB burst); #pragma unroll 4
// bounds scheduler pipelining (round-18-proven no-spill at the 64-reg cap).
// LDS: Abuf only (16 KB). Plain __syncthreads (no DMA to preserve).
// Cvt blocks: H (32MB f32) -> Hbf (16MB bf16), hidden under chain runtime.
// Epilogue: Gtl = g*A10 + (1-g)I PRE-TILED, eg16 = wave*2+m (round 14).
// ---------------------------------------------------------------------------
__global__ __launch_bounds__(1024) void chain_kernel(
    const unsigned short* __restrict__ Ltl,   // tiled L (see prep)
    const float* __restrict__ prec,
    const float* __restrict__ gate_alpha,
    unsigned short* __restrict__ Gtl,         // tiled G, diag folded
    const float* __restrict__ H,
    unsigned short* __restrict__ Hbf,
    const int nCvtBlocks)
{
    const int tid = threadIdx.x;

    if (blockIdx.x >= 32) {
        // ---- H -> bf16 conversion (independent of chain state) ----
        const unsigned gtid = (blockIdx.x - 32) * 1024u + tid;
        const unsigned stride = (unsigned)nCvtBlocks * 1024u * 8u;
        for (size_t i = (size_t)gtid * 8; i < H_ELEMS; i += stride) {
            const float4 v0 = *(const float4*)(H + i);
            const float4 v1 = *(const float4*)(H + i + 4);
            *(short8*)(Hbf + i) = pack8(v0, v1);
        }
        return;
    }

    const int wave = tid >> 6, lane = tid & 63;
    const int lrow = lane & 15, q = lane >> 4;
    const int c_glob = blockIdx.x * 16 + lrow;
    const int ebase = wave * 32;               // 2 m-frags

    __shared__ unsigned short Abuf[16 * D_DIM];    // 16 KiB, swizzled [c][d]
    char* abuf = (char*)Abuf;

    // prec hoisted (8 regs)
    float pr[2][4];
#pragma unroll
    for (int m = 0; m < 2; ++m) {
        const float4 pm = *(const float4*)(prec + ebase + m * 16 + q * 4);
        pr[m][0] = pm.x; pr[m][1] = pm.y; pr[m][2] = pm.z; pr[m][3] = pm.w;
    }

    floatx4 At[2], Bt[2];
#pragma unroll
    for (int m = 0; m < 2; ++m) {
#pragma unroll
        for (int j = 0; j < 4; ++j) {
            const int e = ebase + m * 16 + q * 4 + j;
            At[m][j] = (e == c_glob) ? 1.0f : 0.0f;
            Bt[m][j] = 0.0f;
        }
    }

    // init Abuf with A0 = I (16 waves cover d-cols 0..511)
#pragma unroll
    for (int m = 0; m < 2; ++m) {
        ushortx4 pk;
#pragma unroll
        for (int j = 0; j < 4; ++j) pk[j] = f32_to_bf16(At[m][j]);
        int byte = lrow * 1024 + (ebase + m * 16 + q * 4) * 2;
        byte ^= (lrow & 7) << 4;
        *(ushortx4*)(abuf + byte) = pk;
    }
    __syncthreads();

    // lane's L-frag base: rows [32w,32w+32) are eg32=w; frag (m,kk) at
    //   lb + (kk*2 + m)*1024
    const char* lb = (const char*)Ltl + ((size_t)(wave * 32) << 10) + (size_t)lane * 16;

    for (int step = 0; step < NSTEPS; ++step) {
        floatx4 acc[2] = {};
#pragma unroll 4
        for (int kk = 0; kk < 16; ++kk) {
            const short8 a0 = *(const short8*)(lb + ((kk * 2) << 10));
            const short8 a1 = *(const short8*)(lb + ((kk * 2 + 1) << 10));
            int bbyte = lrow * 1024 + kk * 64 + q * 16;
            bbyte ^= (lrow & 7) << 4;
            const short8 b = *(const short8*)(abuf + bbyte);
            acc[0] = __builtin_amdgcn_mfma_f32_16x16x32_bf16(a0, b, acc[0], 0, 0, 0);
            acc[1] = __builtin_amdgcn_mfma_f32_16x16x32_bf16(a1, b, acc[1], 0, 0, 0);
        }

        // state update (f32, registers only)
#pragma unroll
        for (int m = 0; m < 2; ++m) {
#pragma unroll
            for (int j = 0; j < 4; ++j) {
                const int e = ebase + m * 16 + q * 4 + j;
                const float p = pr[m][j];
                const float tgt = (e == c_glob) ? p : 0.0f;
                const float force = -acc[m][j] - (ALPHA0 + p) * At[m][j]
                                    + tgt - BETA_C * Bt[m][j];
                Bt[m][j] += DT_C * force;
                At[m][j] += DT_C * Bt[m][j];
            }
        }

        if (step < NSTEPS - 1) {
            __syncthreads();
#pragma unroll
            for (int m = 0; m < 2; ++m) {
                ushortx4 pk;
#pragma unroll
                for (int j = 0; j < 4; ++j) pk[j] = f32_to_bf16(At[m][j]);
                int byte = lrow * 1024 + (ebase + m * 16 + q * 4) * 2;
                byte ^= (lrow & 7) << 4;
                *(ushortx4*)(abuf + byte) = pk;
            }
            __syncthreads();
        }
    }

    // epilogue: G = g*A10 + (1-g)I, PRE-TILED (fragment order), eg16=wave*2+m
    const float g = tanhf(gate_alpha[0]);
    const int kt = c_glob >> 5;
    const int lq = ((c_glob >> 3) & 3) * 16;
    const int jb = (c_glob & 7) * 2;
#pragma unroll
    for (int m = 0; m < 2; ++m) {
        char* tbase = (char*)Gtl + ((size_t)((wave * 2 + m) * 16 + kt) << 10);
#pragma unroll
        for (int j = 0; j < 4; ++j) {
            const int e = ebase + m * 16 + q * 4 + j;
            float val = g * At[m][j];
            if (e == c_glob) val += (1.0f - g);
            *(unsigned short*)(tbase + (q * 4 + j + lq) * 16 + jb) = f32_to_bf16(val);
        }
    }
}

// ---------------------------------------------------------------------------
// Kernel 3: out = Hbf @ G^T (diag folded into G). Round-15/16 structure
// (measured ~22us) + optional pre-converted Hbf input (halves H HBM read).
// 64-row tiles, 256 blocks x 256 thr (4 waves); H in 64 KB swizzled LDS;
// G direct from L2 in fragment order (Gtl, 1KB coalesced per frag).
// ---------------------------------------------------------------------------
__global__ __launch_bounds__(256) void out_gemm(
    const float* __restrict__ H,              // [16384][512] f32
    const unsigned short* __restrict__ Hbf,   // [16384][512] bf16 (optional)
    const unsigned short* __restrict__ Gtl,   // tiled G, diag folded
    float* __restrict__ Out,
    const int useHbf)
{
    const int r0 = blockIdx.x * 64;
    const int tid = threadIdx.x;
    const int wave = tid >> 6, lane = tid & 63;
    const int lrow = lane & 15, q = lane >> 4;

    __shared__ unsigned short hlds[64 * D_DIM];  // 64 KiB, swizzled
    char* lds = (char*)hlds;

    // stage H: wave w rows [16w, 16w+16); lane covers cols [8*lane, +8)
    if (useHbf) {
#pragma unroll
        for (int i = 0; i < 16; ++i) {
            const int row = wave * 16 + i;
            const short8 pk = *(const short8*)(Hbf + (size_t)(r0 + row) * D_DIM + lane * 8);
            int byte = row * 1024 + lane * 16;
            byte ^= (row & 7) << 4;
            *(short8*)(lds + byte) = pk;
        }
    } else {
#pragma unroll
        for (int i = 0; i < 16; ++i) {
            const int row = wave * 16 + i;
            const float* src = H + (size_t)(r0 + row) * D_DIM + lane * 8;
            const float4 v0 = *(const float4*)src;
            const float4 v1 = *(const float4*)(src + 4);
            int byte = row * 1024 + lane * 16;
            byte ^= (row & 7) << 4;
            *(short8*)(lds + byte) = pack8(v0, v1);
        }
    }
    __syncthreads();

    // this wave's G tiles: e-groups [wave*8, wave*8+8), all 16 k-tiles
    const char* gtb = (const char*)Gtl + ((size_t)(wave * 8 * 16) << 10)
                      + ((size_t)lane << 4);

    floatx4 acc[4][8] = {};
#pragma unroll
    for (int kk = 0; kk < 16; ++kk) {
        short8 a[4];
#pragma unroll
        for (int m = 0; m < 4; ++m) {
            const int row = m * 16 + lrow;
            int byte = row * 1024 + kk * 64 + q * 16;
            byte ^= (row & 7) << 4;
            a[m] = *(const short8*)(lds + byte);
        }
#pragma unroll
        for (int nh = 0; nh < 2; ++nh) {
            short8 b[4];
#pragma unroll
            for (int n = 0; n < 4; ++n)
                b[n] = *(const short8*)(gtb + ((size_t)((nh * 4 + n) * 16 + kk) << 10));
#pragma unroll
            for (int n = 0; n < 4; ++n)
#pragma unroll
                for (int m = 0; m < 4; ++m)
                    acc[m][nh * 4 + n] = __builtin_amdgcn_mfma_f32_16x16x32_bf16(
                        a[m], b[n], acc[m][nh * 4 + n], 0, 0, 0);
        }
    }

    // epilogue: Out[r][e] = acc (diag already in G)
#pragma unroll
    for (int m = 0; m < 4; ++m) {
#pragma unroll
        for (int j = 0; j < 4; ++j) {
            const int r = r0 + m * 16 + q * 4 + j;
#pragma unroll
            for (int n = 0; n < 8; ++n) {
                const int e = wave * 128 + n * 16 + lrow;
                Out[(size_t)r * D_DIM + e] = acc[m][n][j];
            }
        }
    }
}

// ---------------------------------------------------------------------------
extern "C" void kernel_launch(void* const* d_in, const int* in_sizes, int n_in,
                              void* d_out, int out_size, void* d_ws, size_t ws_size,
                              hipStream_t stream)
{
    const float* H    = (const float*)d_in[0];   // (4,4096,512)
    const float* W    = (const float*)d_in[1];   // (512,512)
    const float* gate = (const float*)d_in[2];   // (1,)
    const float* prec = (const float*)d_in[3];   // (512,)
    float* out = (float*)d_out;
    char* ws = (char*)d_ws;

    unsigned short* Ltl = (unsigned short*)(ws);                 // 512 KiB (tiled)
    unsigned short* Gtl = (unsigned short*)(ws + (512u << 10));  // 512 KiB (tiled)
    unsigned short* Hbf = (unsigned short*)(ws + (1024u << 10)); // 16 MiB (bf16 H)

    const size_t needHbf = (1024u << 10) + (size_t)H_ELEMS * 2;
    const int useHbf = (ws_size >= needHbf) ? 1 : 0;
    const int nCvtBlocks = 224;

    prep_kernel<<<dim3(D_DIM), dim3(64), 0, stream>>>(W, Ltl);

    chain_kernel<<<dim3(useHbf ? 32 + nCvtBlocks : 32), dim3(1024), 0, stream>>>(
        Ltl, prec, gate, Gtl, H, Hbf, nCvtBlocks);

    out_gemm<<<dim3(16384 / 64), dim3(256), 0, stream>>>(H, Hbf, Gtl, out, useHbf);
}

// Round 20
// 78.763 us; speedup vs baseline: 1.5716x; 1.0633x over previous
//
#include <hip/hip_runtime.h>
#include <stdint.h>

#define D_DIM 512
#define NSTEPS 10
#define ALPHA0 0.1f
#define DT_C 0.1f
#define BETA_C 2.8982753492378875f
#define H_ELEMS (16384u * 512u)

typedef __attribute__((ext_vector_type(8))) short short8;
typedef __attribute__((ext_vector_type(4))) float floatx4;
typedef __attribute__((ext_vector_type(4))) unsigned short ushortx4;

__device__ __forceinline__ unsigned short f32_to_bf16(float f) {
    union { float f; uint32_t u; } v;
    v.f = f;
    uint32_t u = v.u;
    return (unsigned short)((u + 0x7FFFu + ((u >> 16) & 1u)) >> 16);
}

__device__ __forceinline__ short8 pack8(const float4 v0, const float4 v1) {
    short8 pk;
    pk[0] = (short)f32_to_bf16(v0.x); pk[1] = (short)f32_to_bf16(v0.y);
    pk[2] = (short)f32_to_bf16(v0.z); pk[3] = (short)f32_to_bf16(v0.w);
    pk[4] = (short)f32_to_bf16(v1.x); pk[5] = (short)f32_to_bf16(v1.y);
    pk[6] = (short)f32_to_bf16(v1.z); pk[7] = (short)f32_to_bf16(v1.w);
    return pk;
}

// ---------------------------------------------------------------------------
// Kernel 1: build L_rw and store PRE-TILED in MFMA fragment order (round 13).
// ---------------------------------------------------------------------------
__global__ __launch_bounds__(64) void prep_kernel(
    const float* __restrict__ W,
    unsigned short* __restrict__ Ltl)    // 512 KiB, tiled layout
{
    const int e = blockIdx.x;
    const int lane = threadIdx.x;
    const float* w = W + (size_t)e * D_DIM + lane * 8;
    const float4 v0 = *(const float4*)w;
    const float4 v1 = *(const float4*)(w + 4);
    float a[8] = { fabsf(v0.x), fabsf(v0.y), fabsf(v0.z), fabsf(v0.w),
                   fabsf(v1.x), fabsf(v1.y), fabsf(v1.z), fabsf(v1.w) };
    float s = a[0] + a[1] + a[2] + a[3] + a[4] + a[5] + a[6] + a[7];
#pragma unroll
    for (int off = 1; off < 64; off <<= 1) s += __shfl_xor(s, off, 64);
    const float inv = 1.0f / fmaxf(s, 1e-8f);
    short8 pk;
#pragma unroll
    for (int j = 0; j < 8; ++j) {
        const float diag = ((lane * 8 + j) == e) ? 1.0f : 0.0f;
        pk[j] = (short)f32_to_bf16(diag - a[j] * inv);
    }
    const int eg = e >> 5, half = (e >> 4) & 1, r = e & 15;
    const int kk = lane >> 2, qp = lane & 3;
    char* dst = (char*)Ltl + ((size_t)(eg * 32 + kk * 2 + half) << 10)
                + ((size_t)(qp * 16 + r) << 4);
    *(short8*)dst = pk;
}

// ---------------------------------------------------------------------------
// Kernel 2: fused {10-step settle (blocks 0..31)} + {H->bf16 cvt (blocks 32+)}.
// Chain: 32 blocks x 1024 thr (16 waves); wave w owns e-rows [32w,32w+32).
// Round-19 structure (50.4us, VGPR 44, no spill) + ROUND-20 change:
//   PERSIST kk-tiles 0..3 of L in wave-private LDS (8 KB/wave, 128 KB total,
//   loaded once before the step loop) -> per-step L2 ingest drops 512->384 KB
//   (chain is at the per-CU L2 ingest wall: 102 GB/s/CU measured r19).
//   LDS total = 16 KB Abuf + 128 KB Lpers = 144 KB (size proven r11-r14).
//   kk-loop split: kk<4 LDS-sourced, kk>=4 L2-sourced with #pragma unroll 4
//   (bounded pipelining -- the r18-proven no-spill idiom).
// Cvt blocks: H (32MB f32) -> Hbf (16MB bf16), hidden under chain runtime.
// Epilogue: Gtl = g*A10 + (1-g)I PRE-TILED, eg16 = wave*2+m.
// ---------------------------------------------------------------------------
__global__ __launch_bounds__(1024) void chain_kernel(
    const unsigned short* __restrict__ Ltl,   // tiled L (see prep)
    const float* __restrict__ prec,
    const float* __restrict__ gate_alpha,
    unsigned short* __restrict__ Gtl,         // tiled G, diag folded
    const float* __restrict__ H,
    unsigned short* __restrict__ Hbf,
    const int nCvtBlocks)
{
    const int tid = threadIdx.x;

    if (blockIdx.x >= 32) {
        // ---- H -> bf16 conversion (independent of chain state) ----
        const unsigned gtid = (blockIdx.x - 32) * 1024u + tid;
        const unsigned stride = (unsigned)nCvtBlocks * 1024u * 8u;
        for (size_t i = (size_t)gtid * 8; i < H_ELEMS; i += stride) {
            const float4 v0 = *(const float4*)(H + i);
            const float4 v1 = *(const float4*)(H + i + 4);
            *(short8*)(Hbf + i) = pack8(v0, v1);
        }
        return;
    }

    const int wave = tid >> 6, lane = tid & 63;
    const int lrow = lane & 15, q = lane >> 4;
    const int c_glob = blockIdx.x * 16 + lrow;
    const int ebase = wave * 32;               // 2 m-frags

    __shared__ unsigned short Abuf[16 * D_DIM];          // 16 KiB, swizzled [c][d]
    __shared__ unsigned short Lpers[16][4][2][512];      // 128 KiB wave-private
    char* abuf = (char*)Abuf;
    char* lp = (char*)&Lpers[wave][0][0][0];             // this wave's 8 KiB

    // lane's L-frag base: rows [32w,32w+32) are eg32=w; frag (m,kk) at
    //   lb + (kk*2 + m)*1024
    const char* lb = (const char*)Ltl + ((size_t)(wave * 32) << 10) + (size_t)lane * 16;

    // persist kk-tiles 0..3 (wave-private; no cross-wave hazard)
#pragma unroll
    for (int kk = 0; kk < 4; ++kk) {
        const short8 a0 = *(const short8*)(lb + ((kk * 2) << 10));
        const short8 a1 = *(const short8*)(lb + ((kk * 2 + 1) << 10));
        *(short8*)(lp + kk * 2048 + lane * 16) = a0;
        *(short8*)(lp + kk * 2048 + 1024 + lane * 16) = a1;
    }

    // prec hoisted (8 regs)
    float pr[2][4];
#pragma unroll
    for (int m = 0; m < 2; ++m) {
        const float4 pm = *(const float4*)(prec + ebase + m * 16 + q * 4);
        pr[m][0] = pm.x; pr[m][1] = pm.y; pr[m][2] = pm.z; pr[m][3] = pm.w;
    }

    floatx4 At[2], Bt[2];
#pragma unroll
    for (int m = 0; m < 2; ++m) {
#pragma unroll
        for (int j = 0; j < 4; ++j) {
            const int e = ebase + m * 16 + q * 4 + j;
            At[m][j] = (e == c_glob) ? 1.0f : 0.0f;
            Bt[m][j] = 0.0f;
        }
    }

    // init Abuf with A0 = I (16 waves cover d-cols 0..511)
#pragma unroll
    for (int m = 0; m < 2; ++m) {
        ushortx4 pk;
#pragma unroll
        for (int j = 0; j < 4; ++j) pk[j] = f32_to_bf16(At[m][j]);
        int byte = lrow * 1024 + (ebase + m * 16 + q * 4) * 2;
        byte ^= (lrow & 7) << 4;
        *(ushortx4*)(abuf + byte) = pk;
    }
    __syncthreads();

    for (int step = 0; step < NSTEPS; ++step) {
        floatx4 acc[2] = {};

        // kk 0..3: L from wave-private LDS (persisted)
#pragma unroll
        for (int kk = 0; kk < 4; ++kk) {
            const short8 a0 = *(const short8*)(lp + kk * 2048 + lane * 16);
            const short8 a1 = *(const short8*)(lp + kk * 2048 + 1024 + lane * 16);
            int bbyte = lrow * 1024 + kk * 64 + q * 16;
            bbyte ^= (lrow & 7) << 4;
            const short8 b = *(const short8*)(abuf + bbyte);
            acc[0] = __builtin_amdgcn_mfma_f32_16x16x32_bf16(a0, b, acc[0], 0, 0, 0);
            acc[1] = __builtin_amdgcn_mfma_f32_16x16x32_bf16(a1, b, acc[1], 0, 0, 0);
        }

        // kk 4..15: L streamed from L2 (bounded pipelining: unroll 4)
#pragma unroll 4
        for (int kk = 4; kk < 16; ++kk) {
            const short8 a0 = *(const short8*)(lb + ((kk * 2) << 10));
            const short8 a1 = *(const short8*)(lb + ((kk * 2 + 1) << 10));
            int bbyte = lrow * 1024 + kk * 64 + q * 16;
            bbyte ^= (lrow & 7) << 4;
            const short8 b = *(const short8*)(abuf + bbyte);
            acc[0] = __builtin_amdgcn_mfma_f32_16x16x32_bf16(a0, b, acc[0], 0, 0, 0);
            acc[1] = __builtin_amdgcn_mfma_f32_16x16x32_bf16(a1, b, acc[1], 0, 0, 0);
        }

        // state update (f32, registers only)
#pragma unroll
        for (int m = 0; m < 2; ++m) {
#pragma unroll
            for (int j = 0; j < 4; ++j) {
                const int e = ebase + m * 16 + q * 4 + j;
                const float p = pr[m][j];
                const float tgt = (e == c_glob) ? p : 0.0f;
                const float force = -acc[m][j] - (ALPHA0 + p) * At[m][j]
                                    + tgt - BETA_C * Bt[m][j];
                Bt[m][j] += DT_C * force;
                At[m][j] += DT_C * Bt[m][j];
            }
        }

        if (step < NSTEPS - 1) {
            __syncthreads();
#pragma unroll
            for (int m = 0; m < 2; ++m) {
                ushortx4 pk;
#pragma unroll
                for (int j = 0; j < 4; ++j) pk[j] = f32_to_bf16(At[m][j]);
                int byte = lrow * 1024 + (ebase + m * 16 + q * 4) * 2;
                byte ^= (lrow & 7) << 4;
                *(ushortx4*)(abuf + byte) = pk;
            }
            __syncthreads();
        }
    }

    // epilogue: G = g*A10 + (1-g)I, PRE-TILED (fragment order), eg16=wave*2+m
    const float g = tanhf(gate_alpha[0]);
    const int kt = c_glob >> 5;
    const int lq = ((c_glob >> 3) & 3) * 16;
    const int jb = (c_glob & 7) * 2;
#pragma unroll
    for (int m = 0; m < 2; ++m) {
        char* tbase = (char*)Gtl + ((size_t)((wave * 2 + m) * 16 + kt) << 10);
#pragma unroll
        for (int j = 0; j < 4; ++j) {
            const int e = ebase + m * 16 + q * 4 + j;
            float val = g * At[m][j];
            if (e == c_glob) val += (1.0f - g);
            *(unsigned short*)(tbase + (q * 4 + j + lq) * 16 + jb) = f32_to_bf16(val);
        }
    }
}

// ---------------------------------------------------------------------------
// Kernel 3: out = Hbf @ G^T (diag folded into G). Round-15/16 structure +
// Hbf input + ROUND-20: XCD-aware block swizzle (grid 256 % 8 == 0 -> valid
// simple swizzle) so neighboring tiles' G-reads hit the same XCD L2.
// ---------------------------------------------------------------------------
__global__ __launch_bounds__(256) void out_gemm(
    const float* __restrict__ H,              // [16384][512] f32
    const unsigned short* __restrict__ Hbf,   // [16384][512] bf16 (optional)
    const unsigned short* __restrict__ Gtl,   // tiled G, diag folded
    float* __restrict__ Out,
    const int useHbf)
{
    // XCD swizzle: contiguous chunks per XCD
    const int cpx = gridDim.x >> 3;           // 32
    const int bid = (blockIdx.x & 7) * cpx + (blockIdx.x >> 3);
    const int r0 = bid * 64;
    const int tid = threadIdx.x;
    const int wave = tid >> 6, lane = tid & 63;
    const int lrow = lane & 15, q = lane >> 4;

    __shared__ unsigned short hlds[64 * D_DIM];  // 64 KiB, swizzled
    char* lds = (char*)hlds;

    // stage H: wave w rows [16w, 16w+16); lane covers cols [8*lane, +8)
    if (useHbf) {
#pragma unroll
        for (int i = 0; i < 16; ++i) {
            const int row = wave * 16 + i;
            const short8 pk = *(const short8*)(Hbf + (size_t)(r0 + row) * D_DIM + lane * 8);
            int byte = row * 1024 + lane * 16;
            byte ^= (row & 7) << 4;
            *(short8*)(lds + byte) = pk;
        }
    } else {
#pragma unroll
        for (int i = 0; i < 16; ++i) {
            const int row = wave * 16 + i;
            const float* src = H + (size_t)(r0 + row) * D_DIM + lane * 8;
            const float4 v0 = *(const float4*)src;
            const float4 v1 = *(const float4*)(src + 4);
            int byte = row * 1024 + lane * 16;
            byte ^= (row & 7) << 4;
            *(short8*)(lds + byte) = pack8(v0, v1);
        }
    }
    __syncthreads();

    // this wave's G tiles: e-groups [wave*8, wave*8+8), all 16 k-tiles
    const char* gtb = (const char*)Gtl + ((size_t)(wave * 8 * 16) << 10)
                      + ((size_t)lane << 4);

    floatx4 acc[4][8] = {};
#pragma unroll
    for (int kk = 0; kk < 16; ++kk) {
        short8 a[4];
#pragma unroll
        for (int m = 0; m < 4; ++m) {
            const int row = m * 16 + lrow;
            int byte = row * 1024 + kk * 64 + q * 16;
            byte ^= (row & 7) << 4;
            a[m] = *(const short8*)(lds + byte);
        }
#pragma unroll
        for (int nh = 0; nh < 2; ++nh) {
            short8 b[4];
#pragma unroll
            for (int n = 0; n < 4; ++n)
                b[n] = *(const short8*)(gtb + ((size_t)((nh * 4 + n) * 16 + kk) << 10));
#pragma unroll
            for (int n = 0; n < 4; ++n)
#pragma unroll
                for (int m = 0; m < 4; ++m)
                    acc[m][nh * 4 + n] = __builtin_amdgcn_mfma_f32_16x16x32_bf16(
                        a[m], b[n], acc[m][nh * 4 + n], 0, 0, 0);
        }
    }

    // epilogue: Out[r][e] = acc (diag already in G)
#pragma unroll
    for (int m = 0; m < 4; ++m) {
#pragma unroll
        for (int j = 0; j < 4; ++j) {
            const int r = r0 + m * 16 + q * 4 + j;
#pragma unroll
            for (int n = 0; n < 8; ++n) {
                const int e = wave * 128 + n * 16 + lrow;
                Out[(size_t)r * D_DIM + e] = acc[m][n][j];
            }
        }
    }
}

// ---------------------------------------------------------------------------
extern "C" void kernel_launch(void* const* d_in, const int* in_sizes, int n_in,
                              void* d_out, int out_size, void* d_ws, size_t ws_size,
                              hipStream_t stream)
{
    const float* H    = (const float*)d_in[0];   // (4,4096,512)
    const float* W    = (const float*)d_in[1];   // (512,512)
    const float* gate = (const float*)d_in[2];   // (1,)
    const float* prec = (const float*)d_in[3];   // (512,)
    float* out = (float*)d_out;
    char* ws = (char*)d_ws;

    unsigned short* Ltl = (unsigned short*)(ws);                 // 512 KiB (tiled)
    unsigned short* Gtl = (unsigned short*)(ws + (512u << 10));  // 512 KiB (tiled)
    unsigned short* Hbf = (unsigned short*)(ws + (1024u << 10)); // 16 MiB (bf16 H)

    const size_t needHbf = (1024u << 10) + (size_t)H_ELEMS * 2;
    const int useHbf = (ws_size >= needHbf) ? 1 : 0;
    const int nCvtBlocks = 224;

    prep_kernel<<<dim3(D_DIM), dim3(64), 0, stream>>>(W, Ltl);

    chain_kernel<<<dim3(useHbf ? 32 + nCvtBlocks : 32), dim3(1024), 0, stream>>>(
        Ltl, prec, gate, Gtl, H, Hbf, nCvtBlocks);

    out_gemm<<<dim3(16384 / 64), dim3(256), 0, stream>>>(H, Hbf, Gtl, out, useHbf);
}

// Round 21
// 68.027 us; speedup vs baseline: 1.8197x; 1.1578x over previous
//
#include <hip/hip_runtime.h>
#include <stdint.h>

#define D_DIM 512
#define NSTEPS 10
#define ALPHA0 0.1f
#define DT_C 0.1f
#define BETA_C 2.8982753492378875f
#define H_ELEMS (16384u * 512u)

typedef __attribute__((ext_vector_type(8))) short short8;
typedef __attribute__((ext_vector_type(4))) float floatx4;
typedef __attribute__((ext_vector_type(4))) unsigned short ushortx4;

__device__ __forceinline__ unsigned short f32_to_bf16(float f) {
    union { float f; uint32_t u; } v;
    v.f = f;
    uint32_t u = v.u;
    return (unsigned short)((u + 0x7FFFu + ((u >> 16) & 1u)) >> 16);
}

__device__ __forceinline__ short8 pack8(const float4 v0, const float4 v1) {
    short8 pk;
    pk[0] = (short)f32_to_bf16(v0.x); pk[1] = (short)f32_to_bf16(v0.y);
    pk[2] = (short)f32_to_bf16(v0.z); pk[3] = (short)f32_to_bf16(v0.w);
    pk[4] = (short)f32_to_bf16(v1.x); pk[5] = (short)f32_to_bf16(v1.y);
    pk[6] = (short)f32_to_bf16(v1.z); pk[7] = (short)f32_to_bf16(v1.w);
    return pk;
}

// ---------------------------------------------------------------------------
// Kernel 1: build L_rw and store PRE-TILED in MFMA fragment order (round 13).
// ---------------------------------------------------------------------------
__global__ __launch_bounds__(64) void prep_kernel(
    const float* __restrict__ W,
    unsigned short* __restrict__ Ltl)    // 512 KiB, tiled layout
{
    const int e = blockIdx.x;
    const int lane = threadIdx.x;
    const float* w = W + (size_t)e * D_DIM + lane * 8;
    const float4 v0 = *(const float4*)w;
    const float4 v1 = *(const float4*)(w + 4);
    float a[8] = { fabsf(v0.x), fabsf(v0.y), fabsf(v0.z), fabsf(v0.w),
                   fabsf(v1.x), fabsf(v1.y), fabsf(v1.z), fabsf(v1.w) };
    float s = a[0] + a[1] + a[2] + a[3] + a[4] + a[5] + a[6] + a[7];
#pragma unroll
    for (int off = 1; off < 64; off <<= 1) s += __shfl_xor(s, off, 64);
    const float inv = 1.0f / fmaxf(s, 1e-8f);
    short8 pk;
#pragma unroll
    for (int j = 0; j < 8; ++j) {
        const float diag = ((lane * 8 + j) == e) ? 1.0f : 0.0f;
        pk[j] = (short)f32_to_bf16(diag - a[j] * inv);
    }
    const int eg = e >> 5, half = (e >> 4) & 1, r = e & 15;
    const int kk = lane >> 2, qp = lane & 3;
    char* dst = (char*)Ltl + ((size_t)(eg * 32 + kk * 2 + half) << 10)
                + ((size_t)(qp * 16 + r) << 4);
    *(short8*)dst = pk;
}

// ---------------------------------------------------------------------------
// Kernel 2: fused {10-step settle (blocks 0..31)} + {H->bf16 cvt (blocks 32+)}.
// EXACT round-20 structure (measured 44.3us, VGPR 52, no spill):
// 16 waves; wave w owns e-rows [32w,32w+32); kk-tiles 0..3 persisted in
// wave-private LDS (128 KB) -> per-step L2 ingest 384 KB; kk 4..15 streamed
// L2->VGPR with #pragma unroll 4 (bounded pipelining).
// ---------------------------------------------------------------------------
__global__ __launch_bounds__(1024) void chain_kernel(
    const unsigned short* __restrict__ Ltl,   // tiled L (see prep)
    const float* __restrict__ prec,
    const float* __restrict__ gate_alpha,
    unsigned short* __restrict__ Gtl,         // tiled G, diag folded
    const float* __restrict__ H,
    unsigned short* __restrict__ Hbf,
    const int nCvtBlocks)
{
    const int tid = threadIdx.x;

    if (blockIdx.x >= 32) {
        // ---- H -> bf16 conversion (independent of chain state) ----
        const unsigned gtid = (blockIdx.x - 32) * 1024u + tid;
        const unsigned stride = (unsigned)nCvtBlocks * 1024u * 8u;
        for (size_t i = (size_t)gtid * 8; i < H_ELEMS; i += stride) {
            const float4 v0 = *(const float4*)(H + i);
            const float4 v1 = *(const float4*)(H + i + 4);
            *(short8*)(Hbf + i) = pack8(v0, v1);
        }
        return;
    }

    const int wave = tid >> 6, lane = tid & 63;
    const int lrow = lane & 15, q = lane >> 4;
    const int c_glob = blockIdx.x * 16 + lrow;
    const int ebase = wave * 32;               // 2 m-frags

    __shared__ unsigned short Abuf[16 * D_DIM];          // 16 KiB, swizzled [c][d]
    __shared__ unsigned short Lpers[16][4][2][512];      // 128 KiB wave-private
    char* abuf = (char*)Abuf;
    char* lp = (char*)&Lpers[wave][0][0][0];             // this wave's 8 KiB

    // lane's L-frag base: rows [32w,32w+32) are eg32=w; frag (m,kk) at
    //   lb + (kk*2 + m)*1024
    const char* lb = (const char*)Ltl + ((size_t)(wave * 32) << 10) + (size_t)lane * 16;

    // persist kk-tiles 0..3 (wave-private; no cross-wave hazard)
#pragma unroll
    for (int kk = 0; kk < 4; ++kk) {
        const short8 a0 = *(const short8*)(lb + ((kk * 2) << 10));
        const short8 a1 = *(const short8*)(lb + ((kk * 2 + 1) << 10));
        *(short8*)(lp + kk * 2048 + lane * 16) = a0;
        *(short8*)(lp + kk * 2048 + 1024 + lane * 16) = a1;
    }

    // prec hoisted (8 regs)
    float pr[2][4];
#pragma unroll
    for (int m = 0; m < 2; ++m) {
        const float4 pm = *(const float4*)(prec + ebase + m * 16 + q * 4);
        pr[m][0] = pm.x; pr[m][1] = pm.y; pr[m][2] = pm.z; pr[m][3] = pm.w;
    }

    floatx4 At[2], Bt[2];
#pragma unroll
    for (int m = 0; m < 2; ++m) {
#pragma unroll
        for (int j = 0; j < 4; ++j) {
            const int e = ebase + m * 16 + q * 4 + j;
            At[m][j] = (e == c_glob) ? 1.0f : 0.0f;
            Bt[m][j] = 0.0f;
        }
    }

    // init Abuf with A0 = I (16 waves cover d-cols 0..511)
#pragma unroll
    for (int m = 0; m < 2; ++m) {
        ushortx4 pk;
#pragma unroll
        for (int j = 0; j < 4; ++j) pk[j] = f32_to_bf16(At[m][j]);
        int byte = lrow * 1024 + (ebase + m * 16 + q * 4) * 2;
        byte ^= (lrow & 7) << 4;
        *(ushortx4*)(abuf + byte) = pk;
    }
    __syncthreads();

    for (int step = 0; step < NSTEPS; ++step) {
        floatx4 acc[2] = {};

        // kk 0..3: L from wave-private LDS (persisted)
#pragma unroll
        for (int kk = 0; kk < 4; ++kk) {
            const short8 a0 = *(const short8*)(lp + kk * 2048 + lane * 16);
            const short8 a1 = *(const short8*)(lp + kk * 2048 + 1024 + lane * 16);
            int bbyte = lrow * 1024 + kk * 64 + q * 16;
            bbyte ^= (lrow & 7) << 4;
            const short8 b = *(const short8*)(abuf + bbyte);
            acc[0] = __builtin_amdgcn_mfma_f32_16x16x32_bf16(a0, b, acc[0], 0, 0, 0);
            acc[1] = __builtin_amdgcn_mfma_f32_16x16x32_bf16(a1, b, acc[1], 0, 0, 0);
        }

        // kk 4..15: L streamed from L2 (bounded pipelining: unroll 4)
#pragma unroll 4
        for (int kk = 4; kk < 16; ++kk) {
            const short8 a0 = *(const short8*)(lb + ((kk * 2) << 10));
            const short8 a1 = *(const short8*)(lb + ((kk * 2 + 1) << 10));
            int bbyte = lrow * 1024 + kk * 64 + q * 16;
            bbyte ^= (lrow & 7) << 4;
            const short8 b = *(const short8*)(abuf + bbyte);
            acc[0] = __builtin_amdgcn_mfma_f32_16x16x32_bf16(a0, b, acc[0], 0, 0, 0);
            acc[1] = __builtin_amdgcn_mfma_f32_16x16x32_bf16(a1, b, acc[1], 0, 0, 0);
        }

        // state update (f32, registers only)
#pragma unroll
        for (int m = 0; m < 2; ++m) {
#pragma unroll
            for (int j = 0; j < 4; ++j) {
                const int e = ebase + m * 16 + q * 4 + j;
                const float p = pr[m][j];
                const float tgt = (e == c_glob) ? p : 0.0f;
                const float force = -acc[m][j] - (ALPHA0 + p) * At[m][j]
                                    + tgt - BETA_C * Bt[m][j];
                Bt[m][j] += DT_C * force;
                At[m][j] += DT_C * Bt[m][j];
            }
        }

        if (step < NSTEPS - 1) {
            __syncthreads();
#pragma unroll
            for (int m = 0; m < 2; ++m) {
                ushortx4 pk;
#pragma unroll
                for (int j = 0; j < 4; ++j) pk[j] = f32_to_bf16(At[m][j]);
                int byte = lrow * 1024 + (ebase + m * 16 + q * 4) * 2;
                byte ^= (lrow & 7) << 4;
                *(ushortx4*)(abuf + byte) = pk;
            }
            __syncthreads();
        }
    }

    // epilogue: G = g*A10 + (1-g)I, PRE-TILED (fragment order), eg16=wave*2+m
    const float g = tanhf(gate_alpha[0]);
    const int kt = c_glob >> 5;
    const int lq = ((c_glob >> 3) & 3) * 16;
    const int jb = (c_glob & 7) * 2;
#pragma unroll
    for (int m = 0; m < 2; ++m) {
        char* tbase = (char*)Gtl + ((size_t)((wave * 2 + m) * 16 + kt) << 10);
#pragma unroll
        for (int j = 0; j < 4; ++j) {
            const int e = ebase + m * 16 + q * 4 + j;
            float val = g * At[m][j];
            if (e == c_glob) val += (1.0f - g);
            *(unsigned short*)(tbase + (q * 4 + j + lq) * 16 + jb) = f32_to_bf16(val);
        }
    }
}

// ---------------------------------------------------------------------------
// Kernel 3: out = Hbf @ G^T (diag folded into G).
// ROUND-21 RESTRUCTURE: 8 waves x 512 thr (was 4x256 with acc[4][8]=128 VGPR
// + staging ~210 regs -> only 2 waves/SIMD, G-load latency exposed ~27us).
// Each wave owns 64 cols (4 e-groups): acc[4][4]=64 + b[4]=32 + a per-m (8)
// ~= 115 regs; __launch_bounds__(512,2) caps at 128 -> 2 blocks/CU =
// 16 waves/CU (4/SIMD) of TLP to hide the per-kk G-loads. #pragma unroll 2
// bounds pipelining (r18 idiom). Same 64-row tile, grid 256, XCD swizzle.
// ---------------------------------------------------------------------------
__global__ __launch_bounds__(512, 2) void out_gemm(
    const float* __restrict__ H,              // [16384][512] f32
    const unsigned short* __restrict__ Hbf,   // [16384][512] bf16 (optional)
    const unsigned short* __restrict__ Gtl,   // tiled G, diag folded
    float* __restrict__ Out,
    const int useHbf)
{
    // XCD swizzle: contiguous chunks per XCD (grid 256 % 8 == 0)
    const int cpx = gridDim.x >> 3;           // 32
    const int bid = (blockIdx.x & 7) * cpx + (blockIdx.x >> 3);
    const int r0 = bid * 64;
    const int tid = threadIdx.x;
    const int wave = tid >> 6, lane = tid & 63;
    const int lrow = lane & 15, q = lane >> 4;

    __shared__ unsigned short hlds[64 * D_DIM];  // 64 KiB, swizzled
    char* lds = (char*)hlds;

    // stage H: wave w rows [8w, 8w+8); lane covers cols [8*lane, +8)
    if (useHbf) {
#pragma unroll
        for (int i = 0; i < 8; ++i) {
            const int row = wave * 8 + i;
            const short8 pk = *(const short8*)(Hbf + (size_t)(r0 + row) * D_DIM + lane * 8);
            int byte = row * 1024 + lane * 16;
            byte ^= (row & 7) << 4;
            *(short8*)(lds + byte) = pk;
        }
    } else {
#pragma unroll
        for (int i = 0; i < 8; ++i) {
            const int row = wave * 8 + i;
            const float* src = H + (size_t)(r0 + row) * D_DIM + lane * 8;
            const float4 v0 = *(const float4*)src;
            const float4 v1 = *(const float4*)(src + 4);
            int byte = row * 1024 + lane * 16;
            byte ^= (row & 7) << 4;
            *(short8*)(lds + byte) = pack8(v0, v1);
        }
    }
    __syncthreads();

    // this wave's G tiles: e-groups [wave*4, wave*4+4), all 16 k-tiles
    const char* gtb = (const char*)Gtl + ((size_t)(wave * 4 * 16) << 10)
                      + ((size_t)lane << 4);

    floatx4 acc[4][4] = {};
#pragma unroll 2
    for (int kk = 0; kk < 16; ++kk) {
        short8 b[4];
#pragma unroll
        for (int n = 0; n < 4; ++n)
            b[n] = *(const short8*)(gtb + ((size_t)(n * 16 + kk) << 10));
#pragma unroll
        for (int m = 0; m < 4; ++m) {
            const int row = m * 16 + lrow;
            int byte = row * 1024 + kk * 64 + q * 16;
            byte ^= (row & 7) << 4;
            const short8 a = *(const short8*)(lds + byte);
#pragma unroll
            for (int n = 0; n < 4; ++n)
                acc[m][n] = __builtin_amdgcn_mfma_f32_16x16x32_bf16(a, b[n], acc[m][n], 0, 0, 0);
        }
    }

    // epilogue: Out[r][e] = acc (diag already in G)
#pragma unroll
    for (int m = 0; m < 4; ++m) {
#pragma unroll
        for (int j = 0; j < 4; ++j) {
            const int r = r0 + m * 16 + q * 4 + j;
#pragma unroll
            for (int n = 0; n < 4; ++n) {
                const int e = wave * 64 + n * 16 + lrow;
                Out[(size_t)r * D_DIM + e] = acc[m][n][j];
            }
        }
    }
}

// ---------------------------------------------------------------------------
extern "C" void kernel_launch(void* const* d_in, const int* in_sizes, int n_in,
                              void* d_out, int out_size, void* d_ws, size_t ws_size,
                              hipStream_t stream)
{
    const float* H    = (const float*)d_in[0];   // (4,4096,512)
    const float* W    = (const float*)d_in[1];   // (512,512)
    const float* gate = (const float*)d_in[2];   // (1,)
    const float* prec = (const float*)d_in[3];   // (512,)
    float* out = (float*)d_out;
    char* ws = (char*)d_ws;

    unsigned short* Ltl = (unsigned short*)(ws);                 // 512 KiB (tiled)
    unsigned short* Gtl = (unsigned short*)(ws + (512u << 10));  // 512 KiB (tiled)
    unsigned short* Hbf = (unsigned short*)(ws + (1024u << 10)); // 16 MiB (bf16 H)

    const size_t needHbf = (1024u << 10) + (size_t)H_ELEMS * 2;
    const int useHbf = (ws_size >= needHbf) ? 1 : 0;
    const int nCvtBlocks = 224;

    prep_kernel<<<dim3(D_DIM), dim3(64), 0, stream>>>(W, Ltl);

    chain_kernel<<<dim3(useHbf ? 32 + nCvtBlocks : 32), dim3(1024), 0, stream>>>(
        Ltl, prec, gate, Gtl, H, Hbf, nCvtBlocks);

    out_gemm<<<dim3(16384 / 64), dim3(512), 0, stream>>>(H, Hbf, Gtl, out, useHbf);
}

// Round 22
// 58.915 us; speedup vs baseline: 2.1011x; 1.1547x over previous
//
#include <hip/hip_runtime.h>
#include <stdint.h>

#define D_DIM 512
#define NSTEPS 10
#define ALPHA0 0.1
#define DT_C 0.1
#define BETA_C 2.8982753492378875

typedef __attribute__((ext_vector_type(8))) short short8;
typedef __attribute__((ext_vector_type(4))) float floatx4;

__device__ __forceinline__ unsigned short f32_to_bf16(float f) {
    union { float f; uint32_t u; } v;
    v.f = f;
    uint32_t u = v.u;
    return (unsigned short)((u + 0x7FFFu + ((u >> 16) & 1u)) >> 16);
}
__device__ __forceinline__ float bf16_to_f32(unsigned short h) {
    union { uint32_t u; float f; } v;
    v.u = ((uint32_t)h) << 16;
    return v.f;
}
__device__ __forceinline__ short8 pack8(const float4 v0, const float4 v1) {
    short8 pk;
    pk[0] = (short)f32_to_bf16(v0.x); pk[1] = (short)f32_to_bf16(v0.y);
    pk[2] = (short)f32_to_bf16(v0.z); pk[3] = (short)f32_to_bf16(v0.w);
    pk[4] = (short)f32_to_bf16(v1.x); pk[5] = (short)f32_to_bf16(v1.y);
    pk[6] = (short)f32_to_bf16(v1.z); pk[7] = (short)f32_to_bf16(v1.w);
    return pk;
}

// A-form (fragment-tiled, MFMA A-operand / proven Ltl layout): element (r,k) at
//   half-id = (r>>5)*32 + (k>>5)*2 + ((r>>4)&1), byte ((k>>3&3)*16 + (r&15))*16 + (k&7)*2
// B-form of Y stores Y^T in A-form: value Y[k][c] lives at aform_off(c,k).
__device__ __forceinline__ size_t aform_off(int r, int k) {
    return ((size_t)((r >> 5) * 32 + (k >> 5) * 2 + ((r >> 4) & 1)) << 10)
         + (size_t)(((((k >> 3) & 3) * 16) + (r & 15)) << 4) + (size_t)((k & 7) * 2);
}
// Gtl (r21-proven out_gemm format): half-id = (e>>4)*16 + (c>>5)
__device__ __forceinline__ size_t gtl_off(int e, int c) {
    return ((size_t)((e >> 4) * 16 + (c >> 5)) << 10)
         + (size_t)(((((c >> 3) & 3) * 16) + (e & 15)) << 4) + (size_t)((c & 7) * 2);
}

// ---------------------------------------------------------------------------
// prep2: M = L_rw + diag(alpha0 + p_e), written in A-form AND B-form.
// ---------------------------------------------------------------------------
__global__ __launch_bounds__(64) void prep2(
    const float* __restrict__ W,
    const float* __restrict__ prec,
    unsigned short* __restrict__ AfM,
    unsigned short* __restrict__ BfM)
{
    const int e = blockIdx.x;
    const int lane = threadIdx.x;
    const float* w = W + (size_t)e * D_DIM + lane * 8;
    const float4 v0 = *(const float4*)w;
    const float4 v1 = *(const float4*)(w + 4);
    float a[8] = { fabsf(v0.x), fabsf(v0.y), fabsf(v0.z), fabsf(v0.w),
                   fabsf(v1.x), fabsf(v1.y), fabsf(v1.z), fabsf(v1.w) };
    float s = a[0] + a[1] + a[2] + a[3] + a[4] + a[5] + a[6] + a[7];
#pragma unroll
    for (int off = 1; off < 64; off <<= 1) s += __shfl_xor(s, off, 64);
    const float inv = 1.0f / fmaxf(s, 1e-8f);
    const float madd = (float)ALPHA0 + prec[e];
    unsigned short mv[8];
#pragma unroll
    for (int j = 0; j < 8; ++j) {
        const int d = lane * 8 + j;
        float lv = ((d == e) ? 1.0f : 0.0f) - a[j] * inv;
        if (d == e) lv += madd;
        mv[j] = f32_to_bf16(lv);
    }
    // A-form: 8 contiguous k's -> one 16B store
    short8 pk;
#pragma unroll
    for (int j = 0; j < 8; ++j) pk[j] = (short)mv[j];
    *(short8*)((char*)AfM + aform_off(e, lane * 8)) = pk;
    // B-form: M[e][d] -> aform_off(d, e), scattered 2B stores
#pragma unroll
    for (int j = 0; j < 8; ++j) {
        const int d = lane * 8 + j;
        *(unsigned short*)((char*)BfM + aform_off(d, e)) = mv[j];
    }
}

// ---------------------------------------------------------------------------
// pk<MODE>: C = X * Y (512^3 bf16 MFMA product), 64 blocks x 256 thr (4 waves
// 2x2), 64x64 tile/block, K=512. Operands direct L2->VGPR (A-form X, B-form Y,
// every fragment a coalesced 1KB burst). #pragma unroll 4 bounds pipelining.
//  MODE 0: M2 = M*M          -> write A-form + B-form
//  MODE 1: M3 = M2*M         -> write A-form
//  MODE 2: V  = M3*B2 + (g3 I + g4 M + g5 M2)        -> write B-form
//  MODE 3: G  = (1-g)I + g*(g0 I + g1 M + g2 M2 + M3*V) -> write Gtl
//  (gk(c) = ca_k + cb_k * prec[c], host-computed polynomial coefficients)
// ---------------------------------------------------------------------------
template<int MODE>
__global__ __launch_bounds__(256) void pk(
    const unsigned short* __restrict__ Aop,
    const unsigned short* __restrict__ Bop,
    unsigned short* __restrict__ outA,
    unsigned short* __restrict__ outB,
    const unsigned short* __restrict__ BfM,
    const unsigned short* __restrict__ BfM2,
    const float* __restrict__ prec,
    const float* __restrict__ gate_alpha,
    float ca0, float cb0, float ca1, float cb1, float ca2, float cb2)
{
    const int tid = threadIdx.x;
    const int wave = tid >> 6, lane = tid & 63;
    const int lrow = lane & 15, q = lane >> 4;
    const int br = blockIdx.x >> 3, bc = blockIdx.x & 7;
    const int wr = wave >> 1, wc = wave & 1;
    const int rgA = br * 2 + wr;     // 32-row group of output rows
    const int cgB = bc * 2 + wc;     // 32-col group of output cols

    const char* abase = (const char*)Aop + ((size_t)(rgA * 32) << 10) + (size_t)lane * 16;
    const char* bbase = (const char*)Bop + ((size_t)(cgB * 32) << 10) + (size_t)lane * 16;

    floatx4 acc[2][2] = {};
#pragma unroll 4
    for (int kk = 0; kk < 16; ++kk) {
        short8 av0 = *(const short8*)(abase + ((kk * 2 + 0) << 10));
        short8 av1 = *(const short8*)(abase + ((kk * 2 + 1) << 10));
        short8 bv0 = *(const short8*)(bbase + ((kk * 2 + 0) << 10));
        short8 bv1 = *(const short8*)(bbase + ((kk * 2 + 1) << 10));
        acc[0][0] = __builtin_amdgcn_mfma_f32_16x16x32_bf16(av0, bv0, acc[0][0], 0, 0, 0);
        acc[0][1] = __builtin_amdgcn_mfma_f32_16x16x32_bf16(av0, bv1, acc[0][1], 0, 0, 0);
        acc[1][0] = __builtin_amdgcn_mfma_f32_16x16x32_bf16(av1, bv0, acc[1][0], 0, 0, 0);
        acc[1][1] = __builtin_amdgcn_mfma_f32_16x16x32_bf16(av1, bv1, acc[1][1], 0, 0, 0);
    }

    float g = 0.f;
    if (MODE == 3) g = tanhf(gate_alpha[0]);

#pragma unroll
    for (int n = 0; n < 2; ++n) {
        const int c = cgB * 32 + n * 16 + lrow;
        float g0 = 0.f, g1 = 0.f, g2 = 0.f;
        if (MODE >= 2) {
            const float p = prec[c];
            g0 = ca0 + cb0 * p; g1 = ca1 + cb1 * p; g2 = ca2 + cb2 * p;
        }
#pragma unroll
        for (int m = 0; m < 2; ++m) {
            const int eb = rgA * 32 + m * 16;
#pragma unroll
            for (int j = 0; j < 4; ++j) {
                const int e = eb + q * 4 + j;
                float val = acc[m][n][j];
                if (MODE >= 2) {
                    const float Mec  = bf16_to_f32(*(const unsigned short*)((const char*)BfM  + aform_off(c, e)));
                    const float M2ec = bf16_to_f32(*(const unsigned short*)((const char*)BfM2 + aform_off(c, e)));
                    if (MODE == 2) {
                        val += g1 * Mec + g2 * M2ec;
                        if (e == c) val += g0;
                    } else {
                        val = g * (val + g1 * Mec + g2 * M2ec);
                        if (e == c) val += (1.0f - g) + g * g0;
                    }
                }
                const unsigned short h = f32_to_bf16(val);
                if (MODE == 0 || MODE == 1)
                    *(unsigned short*)((char*)outA + aform_off(e, c)) = h;
                if (MODE == 0 || MODE == 2)
                    *(unsigned short*)((char*)outB + aform_off(c, e)) = h;
                if (MODE == 3)
                    *(unsigned short*)((char*)outA + gtl_off(e, c)) = h;
            }
        }
    }
}

// ---------------------------------------------------------------------------
// ek: B2 = g6 I + g7 M + g8 M2, written directly in B-form (elementwise in
// B-form layout: Bform[c][d]-slot holds X[d][c], and both inputs exist in
// B-form, so this is a pure vectorized map). One 16B chunk per thread.
// ---------------------------------------------------------------------------
__global__ __launch_bounds__(256) void ek(
    const unsigned short* __restrict__ BfM,
    const unsigned short* __restrict__ BfM2,
    const float* __restrict__ prec,
    unsigned short* __restrict__ BfB2,
    float ca6, float cb6, float ca7, float cb7, float ca8, float cb8)
{
    const int chunk = blockIdx.x * 256 + threadIdx.x;    // 0..32767
    const int half = chunk >> 6, l = chunk & 63;
    const int cg = half >> 5, rem = half & 31, kt = rem >> 1, h = rem & 1;
    const int c = cg * 32 + h * 16 + (l & 15);
    const int dbase = kt * 32 + (l >> 4) * 8;
    const float p = prec[c];
    const float g6 = ca6 + cb6 * p, g7 = ca7 + cb7 * p, g8 = ca8 + cb8 * p;
    const short8 vm  = ((const short8*)BfM)[chunk];
    const short8 vm2 = ((const short8*)BfM2)[chunk];
    short8 o;
#pragma unroll
    for (int u = 0; u < 8; ++u) {
        float v = g7 * bf16_to_f32((unsigned short)vm[u])
                + g8 * bf16_to_f32((unsigned short)vm2[u]);
        if (dbase + u == c) v += g6;
        o[u] = (short)f32_to_bf16(v);
    }
    ((short8*)BfB2)[chunk] = o;
}

// ---------------------------------------------------------------------------
// out_gemm: out = H @ G^T (diag folded into G). r21-proven 8-wave structure,
// f32-H staging path, XCD swizzle, Gtl direct from L2 in fragment order.
// ---------------------------------------------------------------------------
__global__ __launch_bounds__(512, 2) void out_gemm(
    const float* __restrict__ H,              // [16384][512] f32
    const unsigned short* __restrict__ Gtl,   // tiled G, diag folded
    float* __restrict__ Out)
{
    const int cpx = gridDim.x >> 3;
    const int bid = (blockIdx.x & 7) * cpx + (blockIdx.x >> 3);
    const int r0 = bid * 64;
    const int tid = threadIdx.x;
    const int wave = tid >> 6, lane = tid & 63;
    const int lrow = lane & 15, q = lane >> 4;

    __shared__ unsigned short hlds[64 * D_DIM];  // 64 KiB, swizzled
    char* lds = (char*)hlds;

#pragma unroll
    for (int i = 0; i < 8; ++i) {
        const int row = wave * 8 + i;
        const float* src = H + (size_t)(r0 + row) * D_DIM + lane * 8;
        const float4 v0 = *(const float4*)src;
        const float4 v1 = *(const float4*)(src + 4);
        int byte = row * 1024 + lane * 16;
        byte ^= (row & 7) << 4;
        *(short8*)(lds + byte) = pack8(v0, v1);
    }
    __syncthreads();

    const char* gtb = (const char*)Gtl + ((size_t)(wave * 4 * 16) << 10)
                      + ((size_t)lane << 4);

    floatx4 acc[4][4] = {};
#pragma unroll 2
    for (int kk = 0; kk < 16; ++kk) {
        short8 b[4];
#pragma unroll
        for (int n = 0; n < 4; ++n)
            b[n] = *(const short8*)(gtb + ((size_t)(n * 16 + kk) << 10));
#pragma unroll
        for (int m = 0; m < 4; ++m) {
            const int row = m * 16 + lrow;
            int byte = row * 1024 + kk * 64 + q * 16;
            byte ^= (row & 7) << 4;
            const short8 a = *(const short8*)(lds + byte);
#pragma unroll
            for (int n = 0; n < 4; ++n)
                acc[m][n] = __builtin_amdgcn_mfma_f32_16x16x32_bf16(a, b[n], acc[m][n], 0, 0, 0);
        }
    }

#pragma unroll
    for (int m = 0; m < 4; ++m) {
#pragma unroll
        for (int j = 0; j < 4; ++j) {
            const int r = r0 + m * 16 + q * 4 + j;
#pragma unroll
            for (int n = 0; n < 4; ++n) {
                const int e = wave * 64 + n * 16 + lrow;
                Out[(size_t)r * D_DIM + e] = acc[m][n][j];
            }
        }
    }
}

// ---------------------------------------------------------------------------
extern "C" void kernel_launch(void* const* d_in, const int* in_sizes, int n_in,
                              void* d_out, int out_size, void* d_ws, size_t ws_size,
                              hipStream_t stream)
{
    const float* H    = (const float*)d_in[0];   // (4,4096,512)
    const float* W    = (const float*)d_in[1];   // (512,512)
    const float* gate = (const float*)d_in[2];   // (1,)
    const float* prec = (const float*)d_in[3];   // (512,)
    float* out = (float*)d_out;
    char* ws = (char*)d_ws;

    // ---- host: exact polynomial coefficients of the 10-step settle ----
    // A_n = P(M) + Q(M) diag(p); B_n = R(M) + S(M) diag(p)
    // B' = (1-b dt) B - dt M A + dt T ; A' = A + dt B'
    double Pc[11] = {0}, Qc[11] = {0}, Rc[11] = {0}, Sc[11] = {0};
    Pc[0] = 1.0;
    const double dtd = DT_C, c1 = 1.0 - BETA_C * DT_C;
    for (int s = 0; s < NSTEPS; ++s) {
        double nR[11], nS[11];
        for (int k = 0; k < 11; ++k) {
            nR[k] = c1 * Rc[k] - dtd * (k > 0 ? Pc[k - 1] : 0.0);
            nS[k] = c1 * Sc[k] - dtd * (k > 0 ? Qc[k - 1] : 0.0);
        }
        nS[0] += dtd;
        for (int k = 0; k < 11; ++k) {
            Rc[k] = nR[k]; Sc[k] = nS[k];
            Pc[k] += dtd * nR[k]; Qc[k] += dtd * nS[k];
        }
    }
    float av[9], bv[9];
    for (int k = 0; k < 9; ++k) { av[k] = (float)Pc[k]; bv[k] = (float)Qc[k]; }
    // degrees 9,10 dropped: |P9|,|P10| ~ (dt^2)^9 * comb ~ 1e-13 * ||M||^9 -> negligible

    // ws layout: 8 x 512 KiB
    unsigned short* AfM  = (unsigned short*)(ws);
    unsigned short* BfM  = (unsigned short*)(ws + (512u << 10));
    unsigned short* AfM2 = (unsigned short*)(ws + (1024u << 10));
    unsigned short* BfM2 = (unsigned short*)(ws + (1536u << 10));
    unsigned short* AfM3 = (unsigned short*)(ws + (2048u << 10));
    unsigned short* BfB2 = (unsigned short*)(ws + (2560u << 10));
    unsigned short* BfV  = (unsigned short*)(ws + (3072u << 10));
    unsigned short* Gtl  = (unsigned short*)(ws + (3584u << 10));

    prep2<<<dim3(D_DIM), dim3(64), 0, stream>>>(W, prec, AfM, BfM);

    // M2 = M*M (both forms)
    pk<0><<<dim3(64), dim3(256), 0, stream>>>(
        AfM, BfM, AfM2, BfM2, nullptr, nullptr, nullptr, nullptr,
        0.f, 0.f, 0.f, 0.f, 0.f, 0.f);
    // M3 = M2*M (A-form)
    pk<1><<<dim3(64), dim3(256), 0, stream>>>(
        AfM2, BfM, AfM3, nullptr, nullptr, nullptr, nullptr, nullptr,
        0.f, 0.f, 0.f, 0.f, 0.f, 0.f);
    // B2 = g6 I + g7 M + g8 M2 (B-form, elementwise)
    ek<<<dim3(128), dim3(256), 0, stream>>>(
        BfM, BfM2, prec, BfB2, av[6], bv[6], av[7], bv[7], av[8], bv[8]);
    // V = M3*B2 + (g3 I + g4 M + g5 M2) (B-form)
    pk<2><<<dim3(64), dim3(256), 0, stream>>>(
        AfM3, BfB2, nullptr, BfV, BfM, BfM2, prec, nullptr,
        av[3], bv[3], av[4], bv[4], av[5], bv[5]);
    // G = (1-g)I + g*(g0 I + g1 M + g2 M2 + M3*V)  -> Gtl
    pk<3><<<dim3(64), dim3(256), 0, stream>>>(
        AfM3, BfV, Gtl, nullptr, BfM, BfM2, prec, gate,
        av[0], bv[0], av[1], bv[1], av[2], bv[2]);

    out_gemm<<<dim3(16384 / 64), dim3(512), 0, stream>>>(H, Gtl, out);
}